// Round 11
// baseline (154.879 us; speedup 1.0000x reference)
//
#include <hip/hip_runtime.h>

static constexpr int   Bn      = 32;
static constexpr int   Tn      = 2000;
static constexpr int   Hn      = 512;
static constexpr int   Ln      = 256;     // max_label_len
static constexpr float kThresh = 0.95f;
static constexpr int   TCHUNK  = 40;
static constexpr int   NTCH    = Tn / TCHUNK;   // 50

// ---------------------------------------------------------------------------
// DIAGNOSTIC ROUND: K1 is launched 3x (idempotent — writes identical values
// every run) + K2 once. R10 gave K1+K2+2ov = 77.5 us; this run's total
// 3*K1+K2+4ov solves for K1, which the rocprof top-5 can never show directly
// (occluded by the harness's ~75 us ws-poison fills).
// K1/K2 bodies are IDENTICAL to R10 (passed, absmax 0.0).
// ---------------------------------------------------------------------------
__global__ __launch_bounds__(64, 1) void cif_scan_table_kernel(
    const float* __restrict__ alphas,
    int*   __restrict__ tf,     // [Bn][Ln] fire timestep
    float* __restrict__ cwv,    // [Bn][Ln] closing weight (dist_completion)
    float* __restrict__ remv,   // [Bn][Ln] remainder weight (opens next seg)
    int*   __restrict__ fcnt) { // [Bn]
  const int b    = blockIdx.x;
  const int lane = threadIdx.x;
  const float4* __restrict__ arow =
      reinterpret_cast<const float4*>(alphas + (size_t)b * Tn);
  constexpr int CV = TCHUNK / 4;   // 10 float4 per chunk

  // ---- Phase A: serial scan, register-only ----
  float integrate = 0.0f;
  int   fc        = 0;
  float my_int    = 0.0f;          // lane `lane` snapshots chunk `lane`
  int   my_fc     = 0;

  float4 cur[CV], nxt[CV];
#pragma unroll
  for (int i = 0; i < CV; ++i) cur[i] = arow[i];

  for (int c = 0; c < NTCH; ++c) {
    if (c + 1 < NTCH) {
#pragma unroll
      for (int i = 0; i < CV; ++i) nxt[i] = arow[(c + 1) * CV + i];
    }
    const bool mine = (c == lane);
    my_int = mine ? integrate : my_int;
    my_fc  = mine ? fc        : my_fc;
#pragma unroll
    for (int i = 0; i < CV; ++i) {
      const float a4[4] = {cur[i].x, cur[i].y, cur[i].z, cur[i].w};
#pragma unroll
      for (int j = 0; j < 4; ++j) {
        const float integ = integrate + a4[j];    // reference op order
        const bool  fire  = integ > kThresh;
        integrate = fire ? (integ - 1.0f) : integ;
        fc += fire ? 1 : 0;
      }
    }
#pragma unroll
    for (int i = 0; i < CV; ++i) cur[i] = nxt[i];
  }
  if (lane == 0) fcnt[b] = fc;

  // ---- Phase B: per-lane chunk replay -> fire table ----
  if (lane < NTCH) {
    const int t0 = lane * TCHUNK;
    const float4* __restrict__ crow =
        reinterpret_cast<const float4*>(alphas + (size_t)b * Tn + t0);
    float av[TCHUNK];
#pragma unroll
    for (int i = 0; i < CV; ++i) {
      const float4 v = crow[i];
      av[4 * i + 0] = v.x; av[4 * i + 1] = v.y;
      av[4 * i + 2] = v.z; av[4 * i + 3] = v.w;
    }
    float ig = my_int;
    int   s  = my_fc;
#pragma unroll
    for (int k = 0; k < TCHUNK; ++k) {
      const float a     = av[k];
      const float integ = ig + a;                 // reference op order
      const bool  fire  = integ > kThresh;
      if (fire) {
        if (s < Ln) {
          const float cw  = 1.0f - ig;            // dist_completion
          const float rem = a - cw;               // remainds
          tf  [b * Ln + s] = t0 + k;
          cwv [b * Ln + s] = cw;
          remv[b * Ln + s] = rem;
        }
        s += 1;
        ig = integ - 1.0f;
      } else {
        ig = integ;
      }
    }
  }
}

__global__ __launch_bounds__(128) void cif_seg_accum_kernel(
    const float* __restrict__ hidden,
    const float* __restrict__ alphas,
    const int*   __restrict__ tf,
    const float* __restrict__ cwv,
    const float* __restrict__ remv,
    const int*   __restrict__ fcnt,
    float* __restrict__ out) {
  const int s   = blockIdx.x;          // 0..Ln-1
  const int b   = blockIdx.y;          // 0..Bn-1
  const int col = threadIdx.x * 4;

  const int fb    = fcnt[b];
  const int limit = fb < Ln ? fb : Ln;

  float* __restrict__ o = out + ((size_t)b * Ln + s) * Hn + col;

  if (s >= limit) {                    // never-fired slot: emit zeros
    *reinterpret_cast<float4*>(o) = make_float4(0.f, 0.f, 0.f, 0.f);
    return;
  }

  const int t_hi   = tf[b * Ln + s];
  const int t_prev = (s > 0) ? tf[b * Ln + s - 1] : -1;

  const float* __restrict__ hbase = hidden + (size_t)b * Tn * Hn + col;
  const float* __restrict__ arow  = alphas + (size_t)b * Tn;

  float4 acc = make_float4(0.f, 0.f, 0.f, 0.f);

  if (s > 0) {                         // opening: frame = rem * h[t_prev]
    const float r  = remv[b * Ln + s - 1];
    const float4 h = *reinterpret_cast<const float4*>(hbase + (size_t)t_prev * Hn);
    acc.x = r * h.x; acc.y = r * h.y; acc.z = r * h.z; acc.w = r * h.w;
  }
  for (int t = t_prev + 1; t < t_hi; ++t) {   // interior: weight = raw alpha
    const float a  = arow[t];
    const float4 h = *reinterpret_cast<const float4*>(hbase + (size_t)t * Hn);
    acc.x += a * h.x; acc.y += a * h.y; acc.z += a * h.z; acc.w += a * h.w;
  }
  {                                    // closing: weight = dist_completion
    const float c  = cwv[b * Ln + s];
    const float4 h = *reinterpret_cast<const float4*>(hbase + (size_t)t_hi * Hn);
    acc.x += c * h.x; acc.y += c * h.y; acc.z += c * h.z; acc.w += c * h.w;
  }
  *reinterpret_cast<float4*>(o) = acc;
}

extern "C" void kernel_launch(void* const* d_in, const int* in_sizes, int n_in,
                              void* d_out, int out_size, void* d_ws, size_t ws_size,
                              hipStream_t stream) {
  const float* hidden = (const float*)d_in[0];
  const float* alphas = (const float*)d_in[1];
  float* out = (float*)d_out;

  // ws layout: tf[B][Ln] i32 (32 KB) | cw[B][Ln] f32 | rem[B][Ln] f32 | fcnt[B]
  int*   tf   = (int*)d_ws;
  float* cwv  = (float*)(tf + (size_t)Bn * Ln);
  float* remv = cwv + (size_t)Bn * Ln;
  int*   fcnt = (int*)(remv + (size_t)Bn * Ln);

  // DIAGNOSTIC: 3x K1 (idempotent). Solves K1 = (this_total - 77.5)/2 - ov.
  cif_scan_table_kernel<<<Bn, 64, 0, stream>>>(alphas, tf, cwv, remv, fcnt);
  cif_scan_table_kernel<<<Bn, 64, 0, stream>>>(alphas, tf, cwv, remv, fcnt);
  cif_scan_table_kernel<<<Bn, 64, 0, stream>>>(alphas, tf, cwv, remv, fcnt);

  dim3 grid(Ln, Bn);   // 8192 independent blocks, one per output slot
  cif_seg_accum_kernel<<<grid, 128, 0, stream>>>(hidden, alphas, tf, cwv,
                                                 remv, fcnt, out);
}